// Round 3
// baseline (249.291 us; speedup 1.0000x reference)
//
#include <hip/hip_runtime.h>
#include <hip/hip_bf16.h>

#define NSENT 4000
#define LSEQ  128
#define VEC   50
#define WSTR  52      // bf16 word-emb row stride (shorts): 50 real + 2 zero, 104 B (8B-aligned)
#define NVOCAB 50002
#define POS   5
#define EMBD  60      // VEC + 2*POS
#define HIDD  230
#define HSTR  232     // padded channel stride for H
#define NBAG  500
#define NREL  25
#define NTILEP 16     // padded N-tile count (15 real, tile 15 = zeros)
#define KSTEPS 6      // K = 192 (3 taps * 64 e-slots), 6 MFMA K-steps of 32
#define ESTR  72      // row stride in bf16 shorts (144 B; row step = 36 banks -> spread)
#define SLOTS 130     // l+1 shift; rows 0/129 are SAME-pad zeros
#define SSTR  (SLOTS * ESTR)   // per-sentence slab size (shorts) = 9360 (18,720 B)

// e-slot mapping (A and B MUST agree):
//   e 0..49  = wemb dims 0..49      (e50,51 = 0)
//   e 52..55 = p1 dims 0..3
//   e 56..59 = p2 dims 0..3
//   e 60     = p1 dim 4, e61 = 0
//   e 62     = p2 dim 4, e63 = 0
typedef __attribute__((ext_vector_type(8))) short short8;   // 8 bf16 = 4 VGPRs
typedef __attribute__((ext_vector_type(4))) float f32x4;

__device__ __forceinline__ unsigned short f2bf(float f) {
    union { float f; unsigned u; } v; v.f = f;
    unsigned u = v.u + 0x7FFF + ((v.u >> 16) & 1);   // RNE
    return (unsigned short)(u >> 16);
}

// packed f32x2 -> bf16x2 (v_cvt_pk_bf16_f32 on gfx950), low short = first arg
__device__ __forceinline__ unsigned pk(float a, float b) {
    __hip_bfloat162 h = __float22bfloat162_rn(float2{a, b});
    union { __hip_bfloat162 h; unsigned u; } c; c.h = h;
    return c.u;
}

// ---- prep_w: wemb [50000][50] f32 -> wbf [50000][52] bf16 (cols 50,51 = 0) ----
// 5.2 MB table ~fits per-XCD L2; halves embed's gather volume and removes its
// cvt chain entirely (embed becomes a pure uint2 copy on 13/16 lanes).
__global__ __launch_bounds__(256) void prep_w(const float* __restrict__ wemb,
                                              unsigned short* __restrict__ wbf) {
    int r = blockIdx.x * 4 + (threadIdx.x >> 6);
    int lane = threadIdx.x & 63;
    if (r < NVOCAB && lane < WSTR)
        wbf[(size_t)r * WSTR + lane] = (lane < VEC) ? f2bf(wemb[(size_t)r * VEC + lane]) : 0;
}

// ---- prep: conv_w [HID][EMB][3] -> Bfrag[ntile][kstep][lane][8] (bf16) ----
// B layout for mfma_f32_16x16x32_bf16: B[n = lane&15][k = (lane>>4)*8 + j]
__global__ __launch_bounds__(256) void prep_b(const float* __restrict__ conv_w,
                                              unsigned short* __restrict__ Bfrag) {
    int idx = blockIdx.x * 256 + threadIdx.x;
    if (idx >= NTILEP * KSTEPS * 64 * 8) return;
    int j    = idx & 7;
    int lane = (idx >> 3) & 63;
    int t    = idx >> 9;
    int ks   = t % KSTEPS;
    int nt   = t / KSTEPS;
    int c    = nt * 16 + (lane & 15);
    int klin = ks * 32 + (lane >> 4) * 8 + j;
    int tap  = klin >> 6;
    int e    = klin & 63;
    float v  = 0.f;
    if (c < HIDD) {
        int eidx = -1;
        if (e < 50)                 eidx = e;             // wemb dims
        else if (e >= 52 && e < 56) eidx = 50 + (e - 52); // p1[0..3]
        else if (e >= 56 && e < 60) eidx = 55 + (e - 56); // p2[0..3]
        else if (e == 60)           eidx = 54;            // p1[4]
        else if (e == 62)           eidx = 59;            // p2[4]
        if (eidx >= 0) v = conv_w[(c * EMBD + eidx) * 3 + tap];
    }
    Bfrag[idx] = f2bf(v);
}

// ---- embed: barrier-free streaming gather -> bf16 slab in GLOBAL memory ----
// Now a pure bf16 row copy for word dims (no cvt): lane j<13 moves one uint2
// (4 shorts) from wbf row to the slab row. Gather volume 51 MB (was 102 f32)
// and the 5.2 MB table is ~L2-resident. Slab layout [sent][130][72] shorts ==
// the conv kernel's proven conflict-free LDS layout incl. zero pad rows.
__global__ __launch_bounds__(256) void embed(
    const int*   __restrict__ X,  const int* __restrict__ P1, const int* __restrict__ P2,
    const unsigned short* __restrict__ wbf,
    const float* __restrict__ p1emb, const float* __restrict__ p2emb,
    unsigned short* __restrict__ slab)
{
    const int snt = blockIdx.x, tid = threadIdx.x;
    unsigned short* base = slab + (size_t)snt * SSTR;

    // zero SAME-pad rows 0 and 129 (e-slots 0..63)
    if (tid < 64) {
        int r = (tid & 32) ? (SLOTS - 1) : 0;
        *(unsigned*)(base + r * ESTR + (tid & 31) * 2) = 0u;
    }

    #pragma unroll
    for (int it = 0; it < (LSEQ * 16) / 256; ++it) {
        int i = tid + it * 256;
        int l = i >> 4, j = i & 15;
        size_t tb = (size_t)snt * LSEQ + l;
        unsigned short* dst = base + (l + 1) * ESTR;
        uint2 v;
        if (j < 13) {                 // shorts 4j..4j+3 of the bf16 row (j=12 brings the 2 zeros)
            v = *(const uint2*)(wbf + (size_t)X[tb] * WSTR + j * 4);
        } else if (j == 13) {         // p1[0..3] -> e52..55
            const float* p = p1emb + P1[tb] * POS;
            v.x = pk(p[0], p[1]); v.y = pk(p[2], p[3]);
        } else if (j == 14) {         // p2[0..3] -> e56..59
            const float* p = p2emb + P2[tb] * POS;
            v.x = pk(p[0], p[1]); v.y = pk(p[2], p[3]);
        } else {                      // tails -> e60..63
            float a  = p1emb[P1[tb] * POS + 4];
            float b2 = p2emb[P2[tb] * POS + 4];
            v.x = pk(a, 0.f); v.y = pk(b2, 0.f);
        }
        *(uint2*)(dst + (j < 13 ? j * 4 : 52 + (j - 13) * 4)) = v;
    }
}

// ---- conv_enc: slab copy -> LDS, MFMA core with 4 N-tiles/wave ----
// 256-thr (4-wave) block, ONE sentence. Each wave owns N-tiles {4w..4w+3}:
// A-fragment reads amortize over 4 B-tiles -> 192 b128/sentence (half of the
// 2-tile structure's 384), halving the LDS-pipe floor which exceeded the MFMA
// floor. Register budget: B 4x6x4=96 + A 24 + acc 16 + maxv 4 + misc ~= 155,
// targeted at 3 waves/SIMD via __launch_bounds__(256,3). A-read geometry
// (ESTR=72, row = mt*16+m+tap) is byte-identical to the proven core.
__global__ __launch_bounds__(256, 3) void conv_enc(
    const unsigned short* __restrict__ slab,
    const unsigned short* __restrict__ Bfrag, const float* __restrict__ conv_b,
    float* __restrict__ H)
{
    __shared__ unsigned short embS[10240];   // 20,480 B = slab (18,720) + copy overrun
    const int b = blockIdx.x, tid = threadIdx.x;
    const int lane = tid & 63;
    const int wave = __builtin_amdgcn_readfirstlane(tid >> 6);
    const int nt0  = wave * 4;
    const int m    = lane & 15;
    const int quad = lane >> 4;

    // ---- stage the sentence slab (contiguous, 16B-aligned, 1280 uint4)
    const uint4* src = (const uint4*)(slab + (size_t)b * SSTR);
    uint4 tmp[5];
    #pragma unroll
    for (int it = 0; it < 5; ++it) tmp[it] = src[tid + it * 256];
    #pragma unroll
    for (int it = 0; it < 5; ++it) *(uint4*)(embS + (size_t)(tid + it * 256) * 8) = tmp[it];
    __builtin_amdgcn_sched_barrier(0);   // keep tmp dead before B-loads (VGPR peak)

    // ---- this wave's 4 B tiles -> registers (96 VGPRs)
    short8 Bw[4][KSTEPS];
    #pragma unroll
    for (int t = 0; t < 4; ++t)
        #pragma unroll
        for (int ks = 0; ks < KSTEPS; ++ks)
            Bw[t][ks] = *(const short8*)(Bfrag + ((size_t)((nt0 + t) * KSTEPS + ks) * 64 + lane) * 8);

    __syncthreads();

    float maxv[4];
    #pragma unroll
    for (int t = 0; t < 4; ++t) maxv[t] = -1e30f;

    #pragma unroll
    for (int mt = 0; mt < 8; ++mt) {
        short8 A[KSTEPS];
        #pragma unroll
        for (int ks = 0; ks < KSTEPS; ++ks) {
            int tap = ks >> 1;
            int col = (ks & 1) * 32 + quad * 8;
            int row = mt * 16 + m + tap;        // slot (l+tap), +1 shift folded in
            A[ks] = *(const short8*)(embS + row * ESTR + col);
        }
        f32x4 acc[4];
        #pragma unroll
        for (int t = 0; t < 4; ++t) acc[t] = (f32x4){0.f, 0.f, 0.f, 0.f};
        #pragma unroll
        for (int ks = 0; ks < KSTEPS; ++ks)
            #pragma unroll
            for (int t = 0; t < 4; ++t)
                acc[t] = __builtin_amdgcn_mfma_f32_16x16x32_bf16(A[ks], Bw[t][ks], acc[t], 0, 0, 0);
        #pragma unroll
        for (int t = 0; t < 4; ++t)
            maxv[t] = fmaxf(maxv[t],
                       fmaxf(fmaxf(acc[t][0], acc[t][1]), fmaxf(acc[t][2], acc[t][3])));
    }

    // reduce quads via xor 16/32 -> bias + relu -> H
    #pragma unroll
    for (int t = 0; t < 4; ++t) {
        float v = maxv[t];
        v = fmaxf(v, __shfl_xor(v, 16));
        v = fmaxf(v, __shfl_xor(v, 32));
        int c = (nt0 + t) * 16 + lane;
        if (lane < 16 && c < HIDD)
            H[(size_t)b * HSTR + c] = fmaxf(v + conv_b[c], 0.f);
    }
}

// ---- fallback: the proven fused encoder (round-0, 183.6us total) ----
// Used when ws_size can't hold slab + wbf. Verbatim proven code (f32 wemb).
__global__ __launch_bounds__(512, 4) void encoder_fused(
    const int*   __restrict__ X,  const int* __restrict__ P1, const int* __restrict__ P2,
    const float* __restrict__ wemb, const float* __restrict__ p1emb, const float* __restrict__ p2emb,
    const unsigned short* __restrict__ Bfrag, const float* __restrict__ conv_b,
    float* __restrict__ H)
{
    __shared__ unsigned short embS[2 * SSTR];   // [sent][slot][e] bf16
    __shared__ int xS[2 * LSEQ], p1S[2 * LSEQ], p2S[2 * LSEQ];
    const int b2 = blockIdx.x * 2, tid = threadIdx.x;
    const int lane = tid & 63;
    const int wave = __builtin_amdgcn_readfirstlane(tid >> 6);
    const int nt0  = wave * 2;
    const int m    = lane & 15;
    const int quad = lane >> 4;

    short8 Bw[2][KSTEPS];
    #pragma unroll
    for (int t = 0; t < 2; ++t)
        #pragma unroll
        for (int ks = 0; ks < KSTEPS; ++ks)
            Bw[t][ks] = *(const short8*)(Bfrag + ((size_t)((nt0 + t) * KSTEPS + ks) * 64 + lane) * 8);

    #pragma unroll
    for (int it = 0; it < 2; ++it) {
        int i = tid + it * 512;
        if (i < 768) {
            int which = i >> 8, l2 = i & 255;
            const int* src = (which == 0) ? X : (which == 1) ? P1 : P2;
            int v = src[(size_t)b2 * LSEQ + l2];
            int* dst = (which == 0) ? xS : (which == 1) ? p1S : p2S;
            dst[l2] = v;
        } else {
            int t = i - 768;
            if (t < 128) {
                int sent = t >> 6;
                int r = (t & 32) ? (SLOTS - 1) : 0;
                *(unsigned*)(embS + sent * SSTR + r * ESTR + (t & 31) * 2) = 0u;
            }
        }
    }
    __syncthreads();

    #pragma unroll
    for (int it = 0; it < (2 * LSEQ * 16) / 512; ++it) {
        int i = tid + it * 512;
        int sent = i >> 11, rem = i & 2047;
        int l = rem >> 4, j = rem & 15;
        int li = sent * LSEQ + l;
        unsigned short* dst = embS + sent * SSTR + (l + 1) * ESTR;
        uint2 v;
        if (j < 13) {
            const float* src = wemb + (size_t)xS[li] * VEC + j * 4;
            float2 fa = *(const float2*)(src);
            float a2 = 0.f, a3 = 0.f;
            if (j < 12) { float2 fb = *(const float2*)(src + 2); a2 = fb.x; a3 = fb.y; }
            v.x = pk(fa.x, fa.y); v.y = pk(a2, a3);
        } else if (j == 13) {
            const float* p = p1emb + p1S[li] * POS;
            v.x = pk(p[0], p[1]); v.y = pk(p[2], p[3]);
        } else if (j == 14) {
            const float* p = p2emb + p2S[li] * POS;
            v.x = pk(p[0], p[1]); v.y = pk(p[2], p[3]);
        } else {
            float a = p1emb[p1S[li] * POS + 4];
            float b = p2emb[p2S[li] * POS + 4];
            v.x = pk(a, 0.f); v.y = pk(b, 0.f);
        }
        *(uint2*)(dst + (j < 13 ? j * 4 : 52 + (j - 13) * 4)) = v;
    }
    __syncthreads();

    #pragma unroll 1
    for (int s = 0; s < 2; ++s) {
        const unsigned short* eb = embS + s * SSTR;
        float maxv[2][4];
        #pragma unroll
        for (int t = 0; t < 2; ++t)
            #pragma unroll
            for (int r = 0; r < 4; ++r) maxv[t][r] = -1e30f;

        #pragma unroll
        for (int mt = 0; mt < 8; ++mt) {
            short8 A[KSTEPS];
            #pragma unroll
            for (int ks = 0; ks < KSTEPS; ++ks) {
                int tap = ks >> 1;
                int col = (ks & 1) * 32 + quad * 8;
                int row = mt * 16 + m + tap;
                A[ks] = *(const short8*)(eb + row * ESTR + col);
            }
            f32x4 acc[2];
            #pragma unroll
            for (int t = 0; t < 2; ++t) acc[t] = (f32x4){0.f, 0.f, 0.f, 0.f};
            #pragma unroll
            for (int ks = 0; ks < KSTEPS; ++ks)
                #pragma unroll
                for (int t = 0; t < 2; ++t)
                    acc[t] = __builtin_amdgcn_mfma_f32_16x16x32_bf16(A[ks], Bw[t][ks], acc[t], 0, 0, 0);
            #pragma unroll
            for (int t = 0; t < 2; ++t)
                #pragma unroll
                for (int r = 0; r < 4; ++r)
                    maxv[t][r] = fmaxf(maxv[t][r], acc[t][r]);
        }

        #pragma unroll
        for (int t = 0; t < 2; ++t) {
            float v = fmaxf(fmaxf(maxv[t][0], maxv[t][1]),
                            fmaxf(maxv[t][2], maxv[t][3]));
            v = fmaxf(v, __shfl_xor(v, 16));
            v = fmaxf(v, __shfl_xor(v, 32));
            int c = (nt0 + t) * 16 + lane;
            if (lane < 16 && c < HIDD)
                H[(size_t)(b2 + s) * HSTR + c] = fmaxf(v + conv_b[c], 0.f);
        }
    }
}

// ---- Kernel 3: one wave per bag, zero barriers, all state in registers ----
__global__ __launch_bounds__(64) void attn(
    const float* __restrict__ H, const float* __restrict__ rel_w, const float* __restrict__ rel_b,
    const int* __restrict__ relation, const int* __restrict__ scope,
    float* __restrict__ out)
{
    const int b = blockIdx.x, lane = threadIdx.x;
    const int start = scope[2 * b];
    int ns = scope[2 * b + 1] - start;
    if (ns > 8) ns = 8;
    const int rel = relation[b];

    float q[4], h[8][4];
    #pragma unroll
    for (int k = 0; k < 4; ++k) {
        int c = lane + 64 * k;
        q[k] = (c < HIDD) ? rel_w[rel * HIDD + c] : 0.f;
    }
    #pragma unroll
    for (int s = 0; s < 8; ++s)
        #pragma unroll
        for (int k = 0; k < 4; ++k) {
            int c = lane + 64 * k;
            h[s][k] = (s < ns && c < HIDD) ? H[(size_t)(start + s) * HSTR + c] : 0.f;
        }

    float logit[8];
    #pragma unroll
    for (int s = 0; s < 8; ++s) {
        float t = q[0] * h[s][0] + q[1] * h[s][1] + q[2] * h[s][2] + q[3] * h[s][3];
        #pragma unroll
        for (int off = 32; off > 0; off >>= 1) t += __shfl_xor(t, off);
        logit[s] = t;   // all lanes hold it
    }

    float mx = -1e30f;
    for (int s = 0; s < ns; ++s) mx = fmaxf(mx, logit[s]);
    float a[8], den = 0.f;
    #pragma unroll
    for (int s = 0; s < 8; ++s) { a[s] = (s < ns) ? expf(logit[s] - mx) : 0.f; den += a[s]; }
    float inv = 1.f / den;

    float rep[4];
    #pragma unroll
    for (int k = 0; k < 4; ++k) {
        float r = 0.f;
        #pragma unroll
        for (int s = 0; s < 8; ++s) r += a[s] * h[s][k];
        rep[k] = r * inv;
    }

    // classifier: 25 rows of rel_w, coalesced wave reads (L2-broadcast)
    #pragma unroll 5
    for (int g = 0; g < NREL; ++g) {
        float t = 0.f;
        #pragma unroll
        for (int k = 0; k < 4; ++k) {
            int c = lane + 64 * k;
            t += (c < HIDD) ? rel_w[g * HIDD + c] * rep[k] : 0.f;
        }
        #pragma unroll
        for (int off = 32; off > 0; off >>= 1) t += __shfl_xor(t, off);
        if (lane == 0) out[b * NREL + g] = t + rel_b[g];
    }
}

extern "C" void kernel_launch(void* const* d_in, const int* in_sizes, int n_in,
                              void* d_out, int out_size, void* d_ws, size_t ws_size,
                              hipStream_t stream) {
    const int*   X        = (const int*)d_in[0];
    const int*   P1       = (const int*)d_in[1];
    const int*   P2       = (const int*)d_in[2];
    const int*   scope    = (const int*)d_in[5];
    const int*   relation = (const int*)d_in[6];
    const float* wemb     = (const float*)d_in[7];
    const float* p1emb    = (const float*)d_in[8];
    const float* p2emb    = (const float*)d_in[9];
    const float* conv_w   = (const float*)d_in[10];
    const float* conv_b   = (const float*)d_in[11];
    const float* rel_w    = (const float*)d_in[12];
    const float* rel_b    = (const float*)d_in[13];

    // workspace layout
    char* ws = (char*)d_ws;
    float* H = (float*)ws;                                   // 4000*232*4 = 3,712,000
    const size_t offB = (size_t)NSENT * HSTR * 4;
    unsigned short* Bfrag = (unsigned short*)(ws + offB);    // 16*6*64*8*2 = 98,304
    const size_t offS = offB + (size_t)NTILEP * KSTEPS * 64 * 8 * 2;
    unsigned short* slab = (unsigned short*)(ws + offS);     // 4000*9360*2 = 74,880,000
    const size_t offW = offS + (size_t)NSENT * SSTR * 2 + 4096;  // +4KB copy-overrun pad
    unsigned short* wbf = (unsigned short*)(ws + offW);      // 50002*52*2 = 5,200,208
    const size_t need = offW + (size_t)NVOCAB * WSTR * 2;

    const int btot = NTILEP * KSTEPS * 64 * 8;
    hipLaunchKernelGGL(prep_b, dim3((btot + 255) / 256), dim3(256), 0, stream,
                       conv_w, Bfrag);
    if (ws_size >= need) {
        hipLaunchKernelGGL(prep_w, dim3((NVOCAB + 3) / 4), dim3(256), 0, stream,
                           wemb, wbf);
        hipLaunchKernelGGL(embed, dim3(NSENT), dim3(256), 0, stream,
                           X, P1, P2, wbf, p1emb, p2emb, slab);
        hipLaunchKernelGGL(conv_enc, dim3(NSENT), dim3(256), 0, stream,
                           slab, Bfrag, conv_b, H);
    } else {
        hipLaunchKernelGGL(encoder_fused, dim3(NSENT / 2), dim3(512), 0, stream,
                           X, P1, P2, wemb, p1emb, p2emb, Bfrag, conv_b, H);
    }
    hipLaunchKernelGGL(attn, dim3(NBAG), dim3(64), 0, stream,
                       H, rel_w, rel_b, relation, scope, (float*)d_out);
}

// Round 4
// 186.190 us; speedup vs baseline: 1.3389x; 1.3389x over previous
//
#include <hip/hip_runtime.h>
#include <hip/hip_bf16.h>

#define NSENT 4000
#define LSEQ  128
#define VEC   50
#define WSTR  52      // bf16 word-emb row stride (shorts): 50 real + 2 zero, 104 B (8B-aligned)
#define NVOCAB 50002
#define POS   5
#define EMBD  60      // VEC + 2*POS
#define HIDD  230
#define HSTR  232     // padded channel stride for H
#define NBAG  500
#define NREL  25
#define NTILEP 16     // padded N-tile count (15 real, tile 15 = zeros)
#define KSTEPS 6      // K = 192 (3 taps * 64 e-slots), 6 MFMA K-steps of 32
#define ESTR  72      // LDS row stride in bf16 shorts (144 B)
#define SLOTS 130     // l+1 shift; rows 0/129 are SAME-pad zeros
#define SSTR  (SLOTS * ESTR)   // per-sentence LDS half

// e-slot mapping (A and B MUST agree):
//   e 0..49  = wemb dims 0..49      (e50,51 = 0)
//   e 52..55 = p1 dims 0..3
//   e 56..59 = p2 dims 0..3
//   e 60     = p1 dim 4, e61 = 0
//   e 62     = p2 dim 4, e63 = 0
typedef __attribute__((ext_vector_type(8))) short short8;   // 8 bf16 = 4 VGPRs
typedef __attribute__((ext_vector_type(4))) float f32x4;

__device__ __forceinline__ unsigned short f2bf(float f) {
    union { float f; unsigned u; } v; v.f = f;
    unsigned u = v.u + 0x7FFF + ((v.u >> 16) & 1);   // RNE
    return (unsigned short)(u >> 16);
}

// packed f32x2 -> bf16x2 (v_cvt_pk_bf16_f32 on gfx950), low short = first arg
__device__ __forceinline__ unsigned pk(float a, float b) {
    __hip_bfloat162 h = __float22bfloat162_rn(float2{a, b});
    union { __hip_bfloat162 h; unsigned u; } c; c.h = h;
    return c.u;
}

// ---- prep_w: wemb [50000][50] f32 -> wbf [50000][52] bf16 (cols 50,51 = 0) ----
// 5.2 MB table ~L2-resident; halves the fused gather volume and removes its
// cvt chain (word lanes become pure uint2 copies).
__global__ __launch_bounds__(256) void prep_w(const float* __restrict__ wemb,
                                              unsigned short* __restrict__ wbf) {
    int r = blockIdx.x * 4 + (threadIdx.x >> 6);
    int lane = threadIdx.x & 63;
    if (r < NVOCAB && lane < WSTR)
        wbf[(size_t)r * WSTR + lane] = (lane < VEC) ? f2bf(wemb[(size_t)r * VEC + lane]) : 0;
}

// ---- prep: conv_w [HID][EMB][3] -> Bfrag[ntile][kstep][lane][8] (bf16) ----
// B layout for mfma_f32_16x16x32_bf16: B[n = lane&15][k = (lane>>4)*8 + j]
__global__ __launch_bounds__(256) void prep_b(const float* __restrict__ conv_w,
                                              unsigned short* __restrict__ Bfrag) {
    int idx = blockIdx.x * 256 + threadIdx.x;
    if (idx >= NTILEP * KSTEPS * 64 * 8) return;
    int j    = idx & 7;
    int lane = (idx >> 3) & 63;
    int t    = idx >> 9;
    int ks   = t % KSTEPS;
    int nt   = t / KSTEPS;
    int c    = nt * 16 + (lane & 15);
    int klin = ks * 32 + (lane >> 4) * 8 + j;
    int tap  = klin >> 6;
    int e    = klin & 63;
    float v  = 0.f;
    if (c < HIDD) {
        int eidx = -1;
        if (e < 50)                 eidx = e;             // wemb dims
        else if (e >= 52 && e < 56) eidx = 50 + (e - 52); // p1[0..3]
        else if (e >= 56 && e < 60) eidx = 55 + (e - 56); // p2[0..3]
        else if (e == 60)           eidx = 54;            // p1[4]
        else if (e == 62)           eidx = 59;            // p2[4]
        if (eidx >= 0) v = conv_w[(c * EMBD + eidx) * 3 + tap];
    }
    Bfrag[idx] = f2bf(v);
}

// ---- Kernel 2: FUSED bf16-gather + conv1d(k=3,SAME) MFMA + maxpool + relu ----
// Structure = the PROVEN round-0 183us encoder VERBATIM (512 thr, 2 sentences
// sequential, 2 N-tiles/wave, 64 VGPR budget, idx staged in LDS). The ONLY
// change: word-dim gather lanes (j<13) copy one uint2 from the pre-converted
// bf16 table instead of loading 4 f32 + cvt — halves gather bytes, deletes
// the cvt VALU chain. R3 proved 4-tile/wave spills (VGPR 84 + 188MB scratch
// writes); R1 proved removing idx staging serializes the gather chain.
// DO NOT perturb: B-load at kernel top, 8-mt inner loop, sentence-sequential
// outer, #pragma unroll 1 on the sentence loop.
// wave w owns N-tiles {2w, 2w+1} for both sentences.
// A-frag A[m=lane&15][k=quad*8+j] from LDS; C tile col=lane&15, row=quad*4+reg
__global__ __launch_bounds__(512, 4) void encoder(
    const int*   __restrict__ X,  const int* __restrict__ P1, const int* __restrict__ P2,
    const unsigned short* __restrict__ wbf,
    const float* __restrict__ p1emb, const float* __restrict__ p2emb,
    const unsigned short* __restrict__ Bfrag, const float* __restrict__ conv_b,
    float* __restrict__ H)
{
    __shared__ unsigned short embS[2 * SSTR];   // [sent][slot][e] bf16
    __shared__ int xS[2 * LSEQ], p1S[2 * LSEQ], p2S[2 * LSEQ];
    const int b2 = blockIdx.x * 2, tid = threadIdx.x;
    const int lane = tid & 63;
    const int wave = __builtin_amdgcn_readfirstlane(tid >> 6);
    const int nt0  = wave * 2;
    const int m    = lane & 15;
    const int quad = lane >> 4;

    // ---- this wave's B fragments -> registers (48 VGPRs), issued first
    short8 Bw[2][KSTEPS];
    #pragma unroll
    for (int t = 0; t < 2; ++t)
        #pragma unroll
        for (int ks = 0; ks < KSTEPS; ++ks)
            Bw[t][ks] = *(const short8*)(Bfrag + ((size_t)((nt0 + t) * KSTEPS + ks) * 64 + lane) * 8);

    // ---- stage index rows (both sentences contiguous) + zero pad rows
    #pragma unroll
    for (int it = 0; it < 2; ++it) {
        int i = tid + it * 512;
        if (i < 768) {
            int which = i >> 8, l2 = i & 255;
            const int* src = (which == 0) ? X : (which == 1) ? P1 : P2;
            int v = src[(size_t)b2 * LSEQ + l2];
            int* dst = (which == 0) ? xS : (which == 1) ? p1S : p2S;
            dst[l2] = v;
        } else {
            int t = i - 768;     // 128 dword-writes: 2 sent x 2 pad rows x 64 shorts
            if (t < 128) {
                int sent = t >> 6;
                int r = (t & 32) ? (SLOTS - 1) : 0;
                *(unsigned*)(embS + sent * SSTR + r * ESTR + (t & 31) * 2) = 0u;
            }
        }
    }
    __syncthreads();

    // ---- gather both sentences: 16 lanes/token; word lanes = pure uint2 copy
    #pragma unroll
    for (int it = 0; it < (2 * LSEQ * 16) / 512; ++it) {
        int i = tid + it * 512;
        int sent = i >> 11, rem = i & 2047;
        int l = rem >> 4, j = rem & 15;
        int li = sent * LSEQ + l;
        unsigned short* dst = embS + sent * SSTR + (l + 1) * ESTR;
        uint2 v;
        if (j < 13) {                 // shorts 4j..4j+3 of bf16 row (j=12 brings the 2 zeros)
            v = *(const uint2*)(wbf + (size_t)xS[li] * WSTR + j * 4);
        } else if (j == 13) {         // p1[0..3] -> e52..55
            const float* p = p1emb + p1S[li] * POS;
            v.x = pk(p[0], p[1]); v.y = pk(p[2], p[3]);
        } else if (j == 14) {         // p2[0..3] -> e56..59
            const float* p = p2emb + p2S[li] * POS;
            v.x = pk(p[0], p[1]); v.y = pk(p[2], p[3]);
        } else {                      // tails -> e60..63
            float a = p1emb[p1S[li] * POS + 4];
            float b = p2emb[p2S[li] * POS + 4];
            v.x = pk(a, 0.f); v.y = pk(b, 0.f);
        }
        *(uint2*)(dst + (j < 13 ? j * 4 : 52 + (j - 13) * 4)) = v;
    }
    __syncthreads();

    // ---- sentences sequentially: live state per iteration = proven budget
    #pragma unroll 1
    for (int s = 0; s < 2; ++s) {
        const unsigned short* eb = embS + s * SSTR;
        float maxv[2][4];
        #pragma unroll
        for (int t = 0; t < 2; ++t)
            #pragma unroll
            for (int r = 0; r < 4; ++r) maxv[t][r] = -1e30f;

        #pragma unroll
        for (int mt = 0; mt < 8; ++mt) {
            short8 A[KSTEPS];
            #pragma unroll
            for (int ks = 0; ks < KSTEPS; ++ks) {
                int tap = ks >> 1;
                int col = (ks & 1) * 32 + quad * 8;
                int row = mt * 16 + m + tap;        // slot (l+tap), +1 shift folded in
                A[ks] = *(const short8*)(eb + row * ESTR + col);
            }
            f32x4 acc[2];
            #pragma unroll
            for (int t = 0; t < 2; ++t) acc[t] = (f32x4){0.f, 0.f, 0.f, 0.f};
            #pragma unroll
            for (int ks = 0; ks < KSTEPS; ++ks)
                #pragma unroll
                for (int t = 0; t < 2; ++t)
                    acc[t] = __builtin_amdgcn_mfma_f32_16x16x32_bf16(A[ks], Bw[t][ks], acc[t], 0, 0, 0);
            #pragma unroll
            for (int t = 0; t < 2; ++t)
                #pragma unroll
                for (int r = 0; r < 4; ++r)
                    maxv[t][r] = fmaxf(maxv[t][r], acc[t][r]);
        }

        // reduce rows (4 regs, then quads via xor 16/32) -> bias + relu -> H
        #pragma unroll
        for (int t = 0; t < 2; ++t) {
            float v = fmaxf(fmaxf(maxv[t][0], maxv[t][1]),
                            fmaxf(maxv[t][2], maxv[t][3]));
            v = fmaxf(v, __shfl_xor(v, 16));
            v = fmaxf(v, __shfl_xor(v, 32));
            int c = (nt0 + t) * 16 + lane;
            if (lane < 16 && c < HIDD)
                H[(size_t)(b2 + s) * HSTR + c] = fmaxf(v + conv_b[c], 0.f);
        }
    }
}

// ---- fallback: the proven round-0 fused encoder with f32 wemb (verbatim) ----
__global__ __launch_bounds__(512, 4) void encoder_f32(
    const int*   __restrict__ X,  const int* __restrict__ P1, const int* __restrict__ P2,
    const float* __restrict__ wemb, const float* __restrict__ p1emb, const float* __restrict__ p2emb,
    const unsigned short* __restrict__ Bfrag, const float* __restrict__ conv_b,
    float* __restrict__ H)
{
    __shared__ unsigned short embS[2 * SSTR];
    __shared__ int xS[2 * LSEQ], p1S[2 * LSEQ], p2S[2 * LSEQ];
    const int b2 = blockIdx.x * 2, tid = threadIdx.x;
    const int lane = tid & 63;
    const int wave = __builtin_amdgcn_readfirstlane(tid >> 6);
    const int nt0  = wave * 2;
    const int m    = lane & 15;
    const int quad = lane >> 4;

    short8 Bw[2][KSTEPS];
    #pragma unroll
    for (int t = 0; t < 2; ++t)
        #pragma unroll
        for (int ks = 0; ks < KSTEPS; ++ks)
            Bw[t][ks] = *(const short8*)(Bfrag + ((size_t)((nt0 + t) * KSTEPS + ks) * 64 + lane) * 8);

    #pragma unroll
    for (int it = 0; it < 2; ++it) {
        int i = tid + it * 512;
        if (i < 768) {
            int which = i >> 8, l2 = i & 255;
            const int* src = (which == 0) ? X : (which == 1) ? P1 : P2;
            int v = src[(size_t)b2 * LSEQ + l2];
            int* dst = (which == 0) ? xS : (which == 1) ? p1S : p2S;
            dst[l2] = v;
        } else {
            int t = i - 768;
            if (t < 128) {
                int sent = t >> 6;
                int r = (t & 32) ? (SLOTS - 1) : 0;
                *(unsigned*)(embS + sent * SSTR + r * ESTR + (t & 31) * 2) = 0u;
            }
        }
    }
    __syncthreads();

    #pragma unroll
    for (int it = 0; it < (2 * LSEQ * 16) / 512; ++it) {
        int i = tid + it * 512;
        int sent = i >> 11, rem = i & 2047;
        int l = rem >> 4, j = rem & 15;
        int li = sent * LSEQ + l;
        unsigned short* dst = embS + sent * SSTR + (l + 1) * ESTR;
        uint2 v;
        if (j < 13) {
            const float* src = wemb + (size_t)xS[li] * VEC + j * 4;
            float2 fa = *(const float2*)(src);
            float a2 = 0.f, a3 = 0.f;
            if (j < 12) { float2 fb = *(const float2*)(src + 2); a2 = fb.x; a3 = fb.y; }
            v.x = pk(fa.x, fa.y); v.y = pk(a2, a3);
        } else if (j == 13) {
            const float* p = p1emb + p1S[li] * POS;
            v.x = pk(p[0], p[1]); v.y = pk(p[2], p[3]);
        } else if (j == 14) {
            const float* p = p2emb + p2S[li] * POS;
            v.x = pk(p[0], p[1]); v.y = pk(p[2], p[3]);
        } else {
            float a = p1emb[p1S[li] * POS + 4];
            float b = p2emb[p2S[li] * POS + 4];
            v.x = pk(a, 0.f); v.y = pk(b, 0.f);
        }
        *(uint2*)(dst + (j < 13 ? j * 4 : 52 + (j - 13) * 4)) = v;
    }
    __syncthreads();

    #pragma unroll 1
    for (int s = 0; s < 2; ++s) {
        const unsigned short* eb = embS + s * SSTR;
        float maxv[2][4];
        #pragma unroll
        for (int t = 0; t < 2; ++t)
            #pragma unroll
            for (int r = 0; r < 4; ++r) maxv[t][r] = -1e30f;

        #pragma unroll
        for (int mt = 0; mt < 8; ++mt) {
            short8 A[KSTEPS];
            #pragma unroll
            for (int ks = 0; ks < KSTEPS; ++ks) {
                int tap = ks >> 1;
                int col = (ks & 1) * 32 + quad * 8;
                int row = mt * 16 + m + tap;
                A[ks] = *(const short8*)(eb + row * ESTR + col);
            }
            f32x4 acc[2];
            #pragma unroll
            for (int t = 0; t < 2; ++t) acc[t] = (f32x4){0.f, 0.f, 0.f, 0.f};
            #pragma unroll
            for (int ks = 0; ks < KSTEPS; ++ks)
                #pragma unroll
                for (int t = 0; t < 2; ++t)
                    acc[t] = __builtin_amdgcn_mfma_f32_16x16x32_bf16(A[ks], Bw[t][ks], acc[t], 0, 0, 0);
            #pragma unroll
            for (int t = 0; t < 2; ++t)
                #pragma unroll
                for (int r = 0; r < 4; ++r)
                    maxv[t][r] = fmaxf(maxv[t][r], acc[t][r]);
        }

        #pragma unroll
        for (int t = 0; t < 2; ++t) {
            float v = fmaxf(fmaxf(maxv[t][0], maxv[t][1]),
                            fmaxf(maxv[t][2], maxv[t][3]));
            v = fmaxf(v, __shfl_xor(v, 16));
            v = fmaxf(v, __shfl_xor(v, 32));
            int c = (nt0 + t) * 16 + lane;
            if (lane < 16 && c < HIDD)
                H[(size_t)(b2 + s) * HSTR + c] = fmaxf(v + conv_b[c], 0.f);
        }
    }
}

// ---- Kernel 3: one wave per bag, zero barriers, all state in registers ----
__global__ __launch_bounds__(64) void attn(
    const float* __restrict__ H, const float* __restrict__ rel_w, const float* __restrict__ rel_b,
    const int* __restrict__ relation, const int* __restrict__ scope,
    float* __restrict__ out)
{
    const int b = blockIdx.x, lane = threadIdx.x;
    const int start = scope[2 * b];
    int ns = scope[2 * b + 1] - start;
    if (ns > 8) ns = 8;
    const int rel = relation[b];

    float q[4], h[8][4];
    #pragma unroll
    for (int k = 0; k < 4; ++k) {
        int c = lane + 64 * k;
        q[k] = (c < HIDD) ? rel_w[rel * HIDD + c] : 0.f;
    }
    #pragma unroll
    for (int s = 0; s < 8; ++s)
        #pragma unroll
        for (int k = 0; k < 4; ++k) {
            int c = lane + 64 * k;
            h[s][k] = (s < ns && c < HIDD) ? H[(size_t)(start + s) * HSTR + c] : 0.f;
        }

    float logit[8];
    #pragma unroll
    for (int s = 0; s < 8; ++s) {
        float t = q[0] * h[s][0] + q[1] * h[s][1] + q[2] * h[s][2] + q[3] * h[s][3];
        #pragma unroll
        for (int off = 32; off > 0; off >>= 1) t += __shfl_xor(t, off);
        logit[s] = t;   // all lanes hold it
    }

    float mx = -1e30f;
    for (int s = 0; s < ns; ++s) mx = fmaxf(mx, logit[s]);
    float a[8], den = 0.f;
    #pragma unroll
    for (int s = 0; s < 8; ++s) { a[s] = (s < ns) ? expf(logit[s] - mx) : 0.f; den += a[s]; }
    float inv = 1.f / den;

    float rep[4];
    #pragma unroll
    for (int k = 0; k < 4; ++k) {
        float r = 0.f;
        #pragma unroll
        for (int s = 0; s < 8; ++s) r += a[s] * h[s][k];
        rep[k] = r * inv;
    }

    // classifier: 25 rows of rel_w, coalesced wave reads (L2-broadcast)
    #pragma unroll 5
    for (int g = 0; g < NREL; ++g) {
        float t = 0.f;
        #pragma unroll
        for (int k = 0; k < 4; ++k) {
            int c = lane + 64 * k;
            t += (c < HIDD) ? rel_w[g * HIDD + c] * rep[k] : 0.f;
        }
        #pragma unroll
        for (int off = 32; off > 0; off >>= 1) t += __shfl_xor(t, off);
        if (lane == 0) out[b * NREL + g] = t + rel_b[g];
    }
}

extern "C" void kernel_launch(void* const* d_in, const int* in_sizes, int n_in,
                              void* d_out, int out_size, void* d_ws, size_t ws_size,
                              hipStream_t stream) {
    const int*   X        = (const int*)d_in[0];
    const int*   P1       = (const int*)d_in[1];
    const int*   P2       = (const int*)d_in[2];
    const int*   scope    = (const int*)d_in[5];
    const int*   relation = (const int*)d_in[6];
    const float* wemb     = (const float*)d_in[7];
    const float* p1emb    = (const float*)d_in[8];
    const float* p2emb    = (const float*)d_in[9];
    const float* conv_w   = (const float*)d_in[10];
    const float* conv_b   = (const float*)d_in[11];
    const float* rel_w    = (const float*)d_in[12];
    const float* rel_b    = (const float*)d_in[13];

    // workspace layout
    char* ws = (char*)d_ws;
    float* H = (float*)ws;                                   // 4000*232*4 = 3,712,000
    const size_t offB = (size_t)NSENT * HSTR * 4;
    unsigned short* Bfrag = (unsigned short*)(ws + offB);    // 16*6*64*8*2 = 98,304
    const size_t offW = offB + (size_t)NTILEP * KSTEPS * 64 * 8 * 2;
    unsigned short* wbf = (unsigned short*)(ws + offW);      // 50002*52*2 = 5,200,208
    const size_t need = offW + (size_t)NVOCAB * WSTR * 2;

    const int btot = NTILEP * KSTEPS * 64 * 8;
    hipLaunchKernelGGL(prep_b, dim3((btot + 255) / 256), dim3(256), 0, stream,
                       conv_w, Bfrag);
    if (ws_size >= need) {
        hipLaunchKernelGGL(prep_w, dim3((NVOCAB + 3) / 4), dim3(256), 0, stream,
                           wemb, wbf);
        hipLaunchKernelGGL(encoder, dim3(NSENT / 2), dim3(512), 0, stream,
                           X, P1, P2, wbf, p1emb, p2emb, Bfrag, conv_b, H);
    } else {
        hipLaunchKernelGGL(encoder_f32, dim3(NSENT / 2), dim3(512), 0, stream,
                           X, P1, P2, wemb, p1emb, p2emb, Bfrag, conv_b, H);
    }
    hipLaunchKernelGGL(attn, dim3(NBAG), dim3(64), 0, stream,
                       H, rel_w, rel_b, relation, scope, (float*)d_out);
}

// Round 5
// 181.778 us; speedup vs baseline: 1.3714x; 1.0243x over previous
//
#include <hip/hip_runtime.h>
#include <hip/hip_bf16.h>

#define NSENT 4000
#define LSEQ  128
#define VEC   50
#define WSTR  52      // bf16 word-emb row stride (shorts): 50 real + 2 zero, 104 B (8B-aligned)
#define NVOCAB 50002
#define POS   5
#define EMBD  60      // VEC + 2*POS
#define HIDD  230
#define HSTR  232     // padded channel stride for H
#define NBAG  500
#define NREL  25
#define NTILEP 16     // padded N-tile count (15 real, tile 15 = zeros)
#define KSTEPS 6      // K = 192 (3 taps * 64 e-slots), 6 MFMA K-steps of 32
#define ESTR  72      // LDS row stride in bf16 shorts (144 B)
#define SLOTS 130     // l+1 shift; rows 0/129 are SAME-pad zeros
#define SSTR  (SLOTS * ESTR)   // per-sentence LDS half
#define WBLOCKS 2540  // prep: wbf part = NVOCAB*13 uint2-threads / 256

// e-slot mapping (A and B MUST agree):
//   e 0..49  = wemb dims 0..49      (e50,51 = 0)
//   e 52..55 = p1 dims 0..3
//   e 56..59 = p2 dims 0..3
//   e 60     = p1 dim 4, e61 = 0
//   e 62     = p2 dim 4, e63 = 0
typedef __attribute__((ext_vector_type(8))) short short8;   // 8 bf16 = 4 VGPRs
typedef __attribute__((ext_vector_type(4))) float f32x4;

__device__ __forceinline__ unsigned short f2bf(float f) {
    union { float f; unsigned u; } v; v.f = f;
    unsigned u = v.u + 0x7FFF + ((v.u >> 16) & 1);   // RNE
    return (unsigned short)(u >> 16);
}

// packed f32x2 -> bf16x2 (v_cvt_pk_bf16_f32 on gfx950), low short = first arg
__device__ __forceinline__ unsigned pk(float a, float b) {
    __hip_bfloat162 h = __float22bfloat162_rn(float2{a, b});
    union { __hip_bfloat162 h; unsigned u; } c; c.h = h;
    return c.u;
}

// ---- merged prep: wbf table cvt (blocks < WBLOCKS) + Bfrag build (rest) ----
// wbf part: one uint2 (4 bf16) per thread, all lanes active, float2 loads
// (wemb row stride 200 B -> 8B-aligned always). 15 MB traffic ~= 3 us, vs the
// R4 prep_w's 12.5k blocks with 75% idle lanes (~11 us) that ate the encoder
// gain. Bfrag layout for mfma_f32_16x16x32_bf16: B[n=lane&15][k=(lane>>4)*8+j]
__global__ __launch_bounds__(256) void prep(const float* __restrict__ conv_w,
                                            const float* __restrict__ wemb,
                                            unsigned short* __restrict__ Bfrag,
                                            unsigned short* __restrict__ wbf) {
    int bid = blockIdx.x;
    if (bid < WBLOCKS) {
        int idx = bid * 256 + threadIdx.x;        // one uint2 (4 shorts) of wbf
        if (idx < NVOCAB * 13) {
            int r = idx / 13, cj = (idx % 13) * 4;
            const float* src = wemb + (size_t)r * VEC + cj;
            float2 a = *(const float2*)src;
            float2 b = (cj < 48) ? *(const float2*)(src + 2) : float2{0.f, 0.f};
            uint2 v; v.x = pk(a.x, a.y); v.y = pk(b.x, b.y);
            *(uint2*)(wbf + (size_t)r * WSTR + cj) = v;
        }
    } else {
        int idx = (bid - WBLOCKS) * 256 + threadIdx.x;
        if (idx >= NTILEP * KSTEPS * 64 * 8) return;
        int j    = idx & 7;
        int lane = (idx >> 3) & 63;
        int t    = idx >> 9;
        int ks   = t % KSTEPS;
        int nt   = t / KSTEPS;
        int c    = nt * 16 + (lane & 15);
        int klin = ks * 32 + (lane >> 4) * 8 + j;
        int tap  = klin >> 6;
        int e    = klin & 63;
        float v  = 0.f;
        if (c < HIDD) {
            int eidx = -1;
            if (e < 50)                 eidx = e;             // wemb dims
            else if (e >= 52 && e < 56) eidx = 50 + (e - 52); // p1[0..3]
            else if (e >= 56 && e < 60) eidx = 55 + (e - 56); // p2[0..3]
            else if (e == 60)           eidx = 54;            // p1[4]
            else if (e == 62)           eidx = 59;            // p2[4]
            if (eidx >= 0) v = conv_w[(c * EMBD + eidx) * 3 + tap];
        }
        Bfrag[idx] = f2bf(v);
    }
}

// ---- standalone prep_b for the fallback path (no wbf region in ws) ----
__global__ __launch_bounds__(256) void prep_b(const float* __restrict__ conv_w,
                                              unsigned short* __restrict__ Bfrag) {
    int idx = blockIdx.x * 256 + threadIdx.x;
    if (idx >= NTILEP * KSTEPS * 64 * 8) return;
    int j    = idx & 7;
    int lane = (idx >> 3) & 63;
    int t    = idx >> 9;
    int ks   = t % KSTEPS;
    int nt   = t / KSTEPS;
    int c    = nt * 16 + (lane & 15);
    int klin = ks * 32 + (lane >> 4) * 8 + j;
    int tap  = klin >> 6;
    int e    = klin & 63;
    float v  = 0.f;
    if (c < HIDD) {
        int eidx = -1;
        if (e < 50)                 eidx = e;
        else if (e >= 52 && e < 56) eidx = 50 + (e - 52);
        else if (e >= 56 && e < 60) eidx = 55 + (e - 56);
        else if (e == 60)           eidx = 54;
        else if (e == 62)           eidx = 59;
        if (eidx >= 0) v = conv_w[(c * EMBD + eidx) * 3 + tap];
    }
    Bfrag[idx] = f2bf(v);
}

// ---- Kernel 2: FUSED bf16-gather + conv1d(k=3,SAME) MFMA + maxpool + relu ----
// VERBATIM from R4 (measured 77.5us, MfmaUtil 26, FETCH 27.5MB). Proven
// structure: 512 thr, 2 sentences sequential, 2 N-tiles/wave, 64 VGPR,
// idx staged in LDS, word gather = uint2 copy from bf16 table.
// R1 proved removing idx staging serializes the gather chain (+40%);
// R3 proved 4-tile/wave spills (VGPR 84 + 188MB scratch). DO NOT perturb:
// B-load at kernel top, 8-mt inner loop, sentence-sequential outer,
// #pragma unroll 1 on the sentence loop.
__global__ __launch_bounds__(512, 4) void encoder(
    const int*   __restrict__ X,  const int* __restrict__ P1, const int* __restrict__ P2,
    const unsigned short* __restrict__ wbf,
    const float* __restrict__ p1emb, const float* __restrict__ p2emb,
    const unsigned short* __restrict__ Bfrag, const float* __restrict__ conv_b,
    float* __restrict__ H)
{
    __shared__ unsigned short embS[2 * SSTR];   // [sent][slot][e] bf16
    __shared__ int xS[2 * LSEQ], p1S[2 * LSEQ], p2S[2 * LSEQ];
    const int b2 = blockIdx.x * 2, tid = threadIdx.x;
    const int lane = tid & 63;
    const int wave = __builtin_amdgcn_readfirstlane(tid >> 6);
    const int nt0  = wave * 2;
    const int m    = lane & 15;
    const int quad = lane >> 4;

    // ---- this wave's B fragments -> registers (48 VGPRs), issued first
    short8 Bw[2][KSTEPS];
    #pragma unroll
    for (int t = 0; t < 2; ++t)
        #pragma unroll
        for (int ks = 0; ks < KSTEPS; ++ks)
            Bw[t][ks] = *(const short8*)(Bfrag + ((size_t)((nt0 + t) * KSTEPS + ks) * 64 + lane) * 8);

    // ---- stage index rows (both sentences contiguous) + zero pad rows
    #pragma unroll
    for (int it = 0; it < 2; ++it) {
        int i = tid + it * 512;
        if (i < 768) {
            int which = i >> 8, l2 = i & 255;
            const int* src = (which == 0) ? X : (which == 1) ? P1 : P2;
            int v = src[(size_t)b2 * LSEQ + l2];
            int* dst = (which == 0) ? xS : (which == 1) ? p1S : p2S;
            dst[l2] = v;
        } else {
            int t = i - 768;     // 128 dword-writes: 2 sent x 2 pad rows x 64 shorts
            if (t < 128) {
                int sent = t >> 6;
                int r = (t & 32) ? (SLOTS - 1) : 0;
                *(unsigned*)(embS + sent * SSTR + r * ESTR + (t & 31) * 2) = 0u;
            }
        }
    }
    __syncthreads();

    // ---- gather both sentences: 16 lanes/token; word lanes = pure uint2 copy
    #pragma unroll
    for (int it = 0; it < (2 * LSEQ * 16) / 512; ++it) {
        int i = tid + it * 512;
        int sent = i >> 11, rem = i & 2047;
        int l = rem >> 4, j = rem & 15;
        int li = sent * LSEQ + l;
        unsigned short* dst = embS + sent * SSTR + (l + 1) * ESTR;
        uint2 v;
        if (j < 13) {                 // shorts 4j..4j+3 of bf16 row (j=12 brings the 2 zeros)
            v = *(const uint2*)(wbf + (size_t)xS[li] * WSTR + j * 4);
        } else if (j == 13) {         // p1[0..3] -> e52..55
            const float* p = p1emb + p1S[li] * POS;
            v.x = pk(p[0], p[1]); v.y = pk(p[2], p[3]);
        } else if (j == 14) {         // p2[0..3] -> e56..59
            const float* p = p2emb + p2S[li] * POS;
            v.x = pk(p[0], p[1]); v.y = pk(p[2], p[3]);
        } else {                      // tails -> e60..63
            float a = p1emb[p1S[li] * POS + 4];
            float b = p2emb[p2S[li] * POS + 4];
            v.x = pk(a, 0.f); v.y = pk(b, 0.f);
        }
        *(uint2*)(dst + (j < 13 ? j * 4 : 52 + (j - 13) * 4)) = v;
    }
    __syncthreads();

    // ---- sentences sequentially: live state per iteration = proven budget
    #pragma unroll 1
    for (int s = 0; s < 2; ++s) {
        const unsigned short* eb = embS + s * SSTR;
        float maxv[2][4];
        #pragma unroll
        for (int t = 0; t < 2; ++t)
            #pragma unroll
            for (int r = 0; r < 4; ++r) maxv[t][r] = -1e30f;

        #pragma unroll
        for (int mt = 0; mt < 8; ++mt) {
            short8 A[KSTEPS];
            #pragma unroll
            for (int ks = 0; ks < KSTEPS; ++ks) {
                int tap = ks >> 1;
                int col = (ks & 1) * 32 + quad * 8;
                int row = mt * 16 + m + tap;        // slot (l+tap), +1 shift folded in
                A[ks] = *(const short8*)(eb + row * ESTR + col);
            }
            f32x4 acc[2];
            #pragma unroll
            for (int t = 0; t < 2; ++t) acc[t] = (f32x4){0.f, 0.f, 0.f, 0.f};
            #pragma unroll
            for (int ks = 0; ks < KSTEPS; ++ks)
                #pragma unroll
                for (int t = 0; t < 2; ++t)
                    acc[t] = __builtin_amdgcn_mfma_f32_16x16x32_bf16(A[ks], Bw[t][ks], acc[t], 0, 0, 0);
            #pragma unroll
            for (int t = 0; t < 2; ++t)
                #pragma unroll
                for (int r = 0; r < 4; ++r)
                    maxv[t][r] = fmaxf(maxv[t][r], acc[t][r]);
        }

        // reduce rows (4 regs, then quads via xor 16/32) -> bias + relu -> H
        #pragma unroll
        for (int t = 0; t < 2; ++t) {
            float v = fmaxf(fmaxf(maxv[t][0], maxv[t][1]),
                            fmaxf(maxv[t][2], maxv[t][3]));
            v = fmaxf(v, __shfl_xor(v, 16));
            v = fmaxf(v, __shfl_xor(v, 32));
            int c = (nt0 + t) * 16 + lane;
            if (lane < 16 && c < HIDD)
                H[(size_t)(b2 + s) * HSTR + c] = fmaxf(v + conv_b[c], 0.f);
        }
    }
}

// ---- fallback: the proven round-0 fused encoder with f32 wemb (verbatim) ----
__global__ __launch_bounds__(512, 4) void encoder_f32(
    const int*   __restrict__ X,  const int* __restrict__ P1, const int* __restrict__ P2,
    const float* __restrict__ wemb, const float* __restrict__ p1emb, const float* __restrict__ p2emb,
    const unsigned short* __restrict__ Bfrag, const float* __restrict__ conv_b,
    float* __restrict__ H)
{
    __shared__ unsigned short embS[2 * SSTR];
    __shared__ int xS[2 * LSEQ], p1S[2 * LSEQ], p2S[2 * LSEQ];
    const int b2 = blockIdx.x * 2, tid = threadIdx.x;
    const int lane = tid & 63;
    const int wave = __builtin_amdgcn_readfirstlane(tid >> 6);
    const int nt0  = wave * 2;
    const int m    = lane & 15;
    const int quad = lane >> 4;

    short8 Bw[2][KSTEPS];
    #pragma unroll
    for (int t = 0; t < 2; ++t)
        #pragma unroll
        for (int ks = 0; ks < KSTEPS; ++ks)
            Bw[t][ks] = *(const short8*)(Bfrag + ((size_t)((nt0 + t) * KSTEPS + ks) * 64 + lane) * 8);

    #pragma unroll
    for (int it = 0; it < 2; ++it) {
        int i = tid + it * 512;
        if (i < 768) {
            int which = i >> 8, l2 = i & 255;
            const int* src = (which == 0) ? X : (which == 1) ? P1 : P2;
            int v = src[(size_t)b2 * LSEQ + l2];
            int* dst = (which == 0) ? xS : (which == 1) ? p1S : p2S;
            dst[l2] = v;
        } else {
            int t = i - 768;
            if (t < 128) {
                int sent = t >> 6;
                int r = (t & 32) ? (SLOTS - 1) : 0;
                *(unsigned*)(embS + sent * SSTR + r * ESTR + (t & 31) * 2) = 0u;
            }
        }
    }
    __syncthreads();

    #pragma unroll
    for (int it = 0; it < (2 * LSEQ * 16) / 512; ++it) {
        int i = tid + it * 512;
        int sent = i >> 11, rem = i & 2047;
        int l = rem >> 4, j = rem & 15;
        int li = sent * LSEQ + l;
        unsigned short* dst = embS + sent * SSTR + (l + 1) * ESTR;
        uint2 v;
        if (j < 13) {
            const float* src = wemb + (size_t)xS[li] * VEC + j * 4;
            float2 fa = *(const float2*)(src);
            float a2 = 0.f, a3 = 0.f;
            if (j < 12) { float2 fb = *(const float2*)(src + 2); a2 = fb.x; a3 = fb.y; }
            v.x = pk(fa.x, fa.y); v.y = pk(a2, a3);
        } else if (j == 13) {
            const float* p = p1emb + p1S[li] * POS;
            v.x = pk(p[0], p[1]); v.y = pk(p[2], p[3]);
        } else if (j == 14) {
            const float* p = p2emb + p2S[li] * POS;
            v.x = pk(p[0], p[1]); v.y = pk(p[2], p[3]);
        } else {
            float a = p1emb[p1S[li] * POS + 4];
            float b = p2emb[p2S[li] * POS + 4];
            v.x = pk(a, 0.f); v.y = pk(b, 0.f);
        }
        *(uint2*)(dst + (j < 13 ? j * 4 : 52 + (j - 13) * 4)) = v;
    }
    __syncthreads();

    #pragma unroll 1
    for (int s = 0; s < 2; ++s) {
        const unsigned short* eb = embS + s * SSTR;
        float maxv[2][4];
        #pragma unroll
        for (int t = 0; t < 2; ++t)
            #pragma unroll
            for (int r = 0; r < 4; ++r) maxv[t][r] = -1e30f;

        #pragma unroll
        for (int mt = 0; mt < 8; ++mt) {
            short8 A[KSTEPS];
            #pragma unroll
            for (int ks = 0; ks < KSTEPS; ++ks) {
                int tap = ks >> 1;
                int col = (ks & 1) * 32 + quad * 8;
                int row = mt * 16 + m + tap;
                A[ks] = *(const short8*)(eb + row * ESTR + col);
            }
            f32x4 acc[2];
            #pragma unroll
            for (int t = 0; t < 2; ++t) acc[t] = (f32x4){0.f, 0.f, 0.f, 0.f};
            #pragma unroll
            for (int ks = 0; ks < KSTEPS; ++ks)
                #pragma unroll
                for (int t = 0; t < 2; ++t)
                    acc[t] = __builtin_amdgcn_mfma_f32_16x16x32_bf16(A[ks], Bw[t][ks], acc[t], 0, 0, 0);
            #pragma unroll
            for (int t = 0; t < 2; ++t)
                #pragma unroll
                for (int r = 0; r < 4; ++r)
                    maxv[t][r] = fmaxf(maxv[t][r], acc[t][r]);
        }

        #pragma unroll
        for (int t = 0; t < 2; ++t) {
            float v = fmaxf(fmaxf(maxv[t][0], maxv[t][1]),
                            fmaxf(maxv[t][2], maxv[t][3]));
            v = fmaxf(v, __shfl_xor(v, 16));
            v = fmaxf(v, __shfl_xor(v, 32));
            int c = (nt0 + t) * 16 + lane;
            if (lane < 16 && c < HIDD)
                H[(size_t)(b2 + s) * HSTR + c] = fmaxf(v + conv_b[c], 0.f);
        }
    }
}

// ---- Kernel 3: one wave per bag, zero barriers, all state in registers ----
__global__ __launch_bounds__(64) void attn(
    const float* __restrict__ H, const float* __restrict__ rel_w, const float* __restrict__ rel_b,
    const int* __restrict__ relation, const int* __restrict__ scope,
    float* __restrict__ out)
{
    const int b = blockIdx.x, lane = threadIdx.x;
    const int start = scope[2 * b];
    int ns = scope[2 * b + 1] - start;
    if (ns > 8) ns = 8;
    const int rel = relation[b];

    float q[4], h[8][4];
    #pragma unroll
    for (int k = 0; k < 4; ++k) {
        int c = lane + 64 * k;
        q[k] = (c < HIDD) ? rel_w[rel * HIDD + c] : 0.f;
    }
    #pragma unroll
    for (int s = 0; s < 8; ++s)
        #pragma unroll
        for (int k = 0; k < 4; ++k) {
            int c = lane + 64 * k;
            h[s][k] = (s < ns && c < HIDD) ? H[(size_t)(start + s) * HSTR + c] : 0.f;
        }

    float logit[8];
    #pragma unroll
    for (int s = 0; s < 8; ++s) {
        float t = q[0] * h[s][0] + q[1] * h[s][1] + q[2] * h[s][2] + q[3] * h[s][3];
        #pragma unroll
        for (int off = 32; off > 0; off >>= 1) t += __shfl_xor(t, off);
        logit[s] = t;   // all lanes hold it
    }

    float mx = -1e30f;
    for (int s = 0; s < ns; ++s) mx = fmaxf(mx, logit[s]);
    float a[8], den = 0.f;
    #pragma unroll
    for (int s = 0; s < 8; ++s) { a[s] = (s < ns) ? expf(logit[s] - mx) : 0.f; den += a[s]; }
    float inv = 1.f / den;

    float rep[4];
    #pragma unroll
    for (int k = 0; k < 4; ++k) {
        float r = 0.f;
        #pragma unroll
        for (int s = 0; s < 8; ++s) r += a[s] * h[s][k];
        rep[k] = r * inv;
    }

    // classifier: 25 rows of rel_w, coalesced wave reads (L2-broadcast)
    #pragma unroll 5
    for (int g = 0; g < NREL; ++g) {
        float t = 0.f;
        #pragma unroll
        for (int k = 0; k < 4; ++k) {
            int c = lane + 64 * k;
            t += (c < HIDD) ? rel_w[g * HIDD + c] * rep[k] : 0.f;
        }
        #pragma unroll
        for (int off = 32; off > 0; off >>= 1) t += __shfl_xor(t, off);
        if (lane == 0) out[b * NREL + g] = t + rel_b[g];
    }
}

extern "C" void kernel_launch(void* const* d_in, const int* in_sizes, int n_in,
                              void* d_out, int out_size, void* d_ws, size_t ws_size,
                              hipStream_t stream) {
    const int*   X        = (const int*)d_in[0];
    const int*   P1       = (const int*)d_in[1];
    const int*   P2       = (const int*)d_in[2];
    const int*   scope    = (const int*)d_in[5];
    const int*   relation = (const int*)d_in[6];
    const float* wemb     = (const float*)d_in[7];
    const float* p1emb    = (const float*)d_in[8];
    const float* p2emb    = (const float*)d_in[9];
    const float* conv_w   = (const float*)d_in[10];
    const float* conv_b   = (const float*)d_in[11];
    const float* rel_w    = (const float*)d_in[12];
    const float* rel_b    = (const float*)d_in[13];

    // workspace layout
    char* ws = (char*)d_ws;
    float* H = (float*)ws;                                   // 4000*232*4 = 3,712,000
    const size_t offB = (size_t)NSENT * HSTR * 4;
    unsigned short* Bfrag = (unsigned short*)(ws + offB);    // 16*6*64*8*2 = 98,304
    const size_t offW = offB + (size_t)NTILEP * KSTEPS * 64 * 8 * 2;
    unsigned short* wbf = (unsigned short*)(ws + offW);      // 50002*52*2 = 5,200,208
    const size_t need = offW + (size_t)NVOCAB * WSTR * 2;

    if (ws_size >= need) {
        // merged prep: wbf cvt (2540 blocks) + Bfrag build (192 blocks)
        hipLaunchKernelGGL(prep, dim3(WBLOCKS + 192), dim3(256), 0, stream,
                           conv_w, wemb, Bfrag, wbf);
        hipLaunchKernelGGL(encoder, dim3(NSENT / 2), dim3(512), 0, stream,
                           X, P1, P2, wbf, p1emb, p2emb, Bfrag, conv_b, H);
    } else {
        const int btot = NTILEP * KSTEPS * 64 * 8;
        hipLaunchKernelGGL(prep_b, dim3((btot + 255) / 256), dim3(256), 0, stream,
                           conv_w, Bfrag);
        hipLaunchKernelGGL(encoder_f32, dim3(NSENT / 2), dim3(512), 0, stream,
                           X, P1, P2, wemb, p1emb, p2emb, Bfrag, conv_b, H);
    }
    hipLaunchKernelGGL(attn, dim3(NBAG), dim3(64), 0, stream,
                       H, rel_w, rel_b, relation, scope, (float*)d_out);
}